// Round 7
// baseline (143.829 us; speedup 1.0000x reference)
//
#include <hip/hip_runtime.h>

#define N_NODES 50000
#define N_EDGES 800000
#define IN_DIM 128
#define OUT_DIM 64
#define CAP 64            // max row degree ~35 (Binomial(800k,1/50k), mean 16), 64 is safe
#define PARTS 8           // row partitions == XCD count
#define ROWS_PER_PART 6250
#define CHUNKS 512
#define EDGES_PER_CHUNK 1563   // 512*1563 = 800256 >= 800000 (guarded)

// Block layout: GEMM blocks FIRST so they are co-resident with the bucket
// blocks. 784%8==0 keeps the bucket blocks' blockIdx%8 == XCD mapping intact.
#define GEMM_BLOCKS 784                  // 784*4 waves = 3136 >= 3125 groups
#define BUCKET_BLOCKS (CHUNKS * PARTS)   // 4096
#define TOTAL_BLOCKS (GEMM_BLOCKS + BUCKET_BLOCKS)

// workspace layout (bytes), 16B-aligned
#define OFF_HID 0u          // bf16 hidden: 50000*64*2 = 6,400,000
#define OFF_DEG 6400000u    // int deg: 200,000
#define OFF_BKT 6600192u    // int2 bucket: 50000*64*8 = 25,600,000  (total ~32 MB)

typedef short short8 __attribute__((ext_vector_type(8)));
typedef float f32x4 __attribute__((ext_vector_type(4)));

__device__ __forceinline__ unsigned short bf_rne(float f) {
    unsigned u = __float_as_uint(f);
    u += 0x7fffu + ((u >> 16) & 1u);   // round-to-nearest-even
    return (unsigned short)(u >> 16);
}
__device__ __forceinline__ float bf_lo(unsigned u) { return __uint_as_float(u << 16); }
__device__ __forceinline__ float bf_hi(unsigned u) { return __uint_as_float(u & 0xffff0000u); }

// ---------------------------------------------------------------------------
// FUSED kernel. blocks [0, 784): MFMA GEMM hidden = x @ w.
// blocks [784, 784+4096): edge bucketing, XCD-partitioned (part = bb&7 ==
// XCD). Each partition re-reads the full edge list (redundancy L3-absorbed)
// but writes ONLY its own 3.2 MB bucket section -> partial 64-B lines merge
// in the home XCD's L2 (R5 proved removing this costs +20 us).
// NEW vs R6: (a) 512 chunks -> 6 edges/thread, ALL loaded up-front, 6 fully
// independent atomic->store chains in straight-line code (was 3 sequential
// 4-deep trips); (b) x loads in the GEMM path are non-temporal (stream-once)
// so they stop evicting bucket partial lines from L2 before they merge —
// edge loads stay CACHED (8x L3 reuse; R4 showed nt there regresses).
// ---------------------------------------------------------------------------
__global__ __launch_bounds__(256) void fused_kernel(
        const float* __restrict__ x, const float* __restrict__ w,
        unsigned short* __restrict__ hidb,
        const int* __restrict__ erow, const int* __restrict__ ecol,
        const float* __restrict__ eval,
        int* __restrict__ deg, int2* __restrict__ bucket) {
    if (blockIdx.x >= GEMM_BLOCKS) {
        const int bb = blockIdx.x - GEMM_BLOCKS;
        const int part = bb & (PARTS - 1);           // == XCD id
        const int chunk = bb >> 3;
        const int rlo = part * ROWS_PER_PART;
        const int e0 = chunk * EDGES_PER_CHUNK;

        // load 6 edges up-front (max i = 255+1280 = 1535 < 1563, so only the
        // global e < N_EDGES bound can fail, and only in the last 8 blocks)
        int r[6], c[6];
        float v[6];
        bool ok[6];
        #pragma unroll
        for (int t = 0; t < 6; ++t) {
            const int e = e0 + threadIdx.x + t * 256;
            ok[t] = e < N_EDGES;
            r[t] = ok[t] ? erow[e] : -1;
            c[t] = ok[t] ? ecol[e] : 0;
            v[t] = ok[t] ? eval[e] : 0.f;
        }
        // 6 independent atomic->store chains
        #pragma unroll
        for (int t = 0; t < 6; ++t) {
            if (ok[t] && (unsigned)(r[t] - rlo) < (unsigned)ROWS_PER_PART) {
                const int pos = atomicAdd(&deg[r[t]], 1);
                if (pos < CAP)
                    bucket[(size_t)r[t] * CAP + pos] = make_int2(c[t], __float_as_int(v[t]));
            }
        }
        // tail: slots 1536..1562 (tid < 27)
        const int it = threadIdx.x + 1536;
        const int e = e0 + it;
        if (it < EDGES_PER_CHUNK && e < N_EDGES) {
            const int rt = erow[e];
            const int ct = ecol[e];
            const float vt = eval[e];
            if ((unsigned)(rt - rlo) < (unsigned)ROWS_PER_PART) {
                const int pos = atomicAdd(&deg[rt], 1);
                if (pos < CAP) bucket[(size_t)rt * CAP + pos] = make_int2(ct, __float_as_int(vt));
            }
        }
        return;
    }

    // ---- GEMM path: hidden(bf16) = x @ w, one wave per 16-node group ----
    __shared__ __attribute__((aligned(16))) unsigned short smem[16 * 64 * 8];  // 16 KB

    const int tid = threadIdx.x;
    const int lane = tid & 63;
    const int wid = tid >> 6;

    // stage w into B-fragment order — coalesced float4 global reads,
    // scattered cheap LDS u16 writes.
    #pragma unroll
    for (int it = 0; it < 8; ++it) {
        const int e = it * 1024 + tid * 4;
        const f32x4 wv = *(const f32x4*)(w + e);
        const int k = e >> 6;
        const int n0 = e & 63;
        const int c = k >> 5, j = k & 7, lhi = ((k >> 3) & 3) * 16;
        #pragma unroll
        for (int m = 0; m < 4; ++m) {
            const int n = n0 + m;
            const int t = n >> 4;
            const int ln = lhi + (n & 15);
            smem[((c * 4 + t) * 64 + ln) * 8 + j] = bf_rne(wv[m]);
        }
    }
    __syncthreads();

    const int group = blockIdx.x * 4 + wid;   // 16-node group id

    short8 bf[16];
    if (group < N_NODES / 16) {
        #pragma unroll
        for (int f = 0; f < 16; ++f)
            bf[f] = *(const short8*)&smem[(f * 64 + lane) * 8];
    }
    __syncthreads();   // all waves have frags in regs -> smem reusable

    if (group < N_NODES / 16) {
        const int node0 = group * 16;
        f32x4 acc[4] = {{0, 0, 0, 0}, {0, 0, 0, 0}, {0, 0, 0, 0}, {0, 0, 0, 0}};

        #pragma unroll
        for (int c = 0; c < 4; ++c) {
            const float* xr = x + (size_t)(node0 + (lane & 15)) * IN_DIM + c * 32 + (lane >> 4) * 8;
            // x is read exactly once -> non-temporal, so the 25.6 MB stream
            // doesn't evict bucket partial lines from L2 (bucket merge).
            const f32x4 a0 = __builtin_nontemporal_load((const f32x4*)xr);
            const f32x4 a1 = __builtin_nontemporal_load((const f32x4*)(xr + 4));
            short8 af;
            af[0] = (short)bf_rne(a0[0]); af[1] = (short)bf_rne(a0[1]);
            af[2] = (short)bf_rne(a0[2]); af[3] = (short)bf_rne(a0[3]);
            af[4] = (short)bf_rne(a1[0]); af[5] = (short)bf_rne(a1[1]);
            af[6] = (short)bf_rne(a1[2]); af[7] = (short)bf_rne(a1[3]);
            #pragma unroll
            for (int t = 0; t < 4; ++t)
                acc[t] = __builtin_amdgcn_mfma_f32_16x16x32_bf16(af, bf[c * 4 + t], acc[t], 0, 0, 0);
        }

        // epilogue: D[m][n] -> smem bounce (wave-private slice) -> global
        // hidb stores stay cached: agg re-reads each row ~16x.
        unsigned short* obuf = smem + wid * 1024;
        #pragma unroll
        for (int t = 0; t < 4; ++t)
            #pragma unroll
            for (int r = 0; r < 4; ++r)
                obuf[((lane >> 4) * 4 + r) * 64 + t * 16 + (lane & 15)] = bf_rne(acc[t][r]);
        const uint4 o0 = *(const uint4*)&obuf[lane * 16];
        const uint4 o1 = *(const uint4*)&obuf[lane * 16 + 8];
        char* dst = (char*)hidb + (size_t)node0 * (OUT_DIM * 2) + lane * 32;
        *(uint4*)dst = o0;
        *(uint4*)(dst + 16) = o1;
    }
}

// ---------------------------------------------------------------------------
// Aggregate (R6 form): 4 rows per wave (quarter q = row, 16 lanes x 8 B cover
// the 128-B hidden row). All loads cached. Gathers issued in 16-deep windows:
// window 1 (slots 0-15) unconditional, window 2 (16-31) under one wave-
// uniform branch, rare tail after.
// ---------------------------------------------------------------------------
__device__ __forceinline__ void proc16(const unsigned short* __restrict__ hidb,
                                       int2 P, int base,
                                       int q, int l, int d, float4& acc) {
    unsigned long long u[16];
    float vv[16];
    #pragma unroll
    for (int e = 0; e < 16; ++e) {
        const int src = q * 16 + e;          // lane holding slot (base+e) of row q
        int c = __shfl(P.x, src);
        const int vi = __shfl(P.y, src);
        const bool act = (base + e) < d;
        c = act ? c : 0;
        vv[e] = act ? __int_as_float(vi) : 0.f;
        u[e] = *(const unsigned long long*)&hidb[(size_t)c * OUT_DIM + 4 * l];
    }
    #pragma unroll
    for (int e = 0; e < 16; ++e) {
        const float v = vv[e];
        const unsigned ulo = (unsigned)u[e];
        const unsigned uhi = (unsigned)(u[e] >> 32);
        acc.x = fmaf(v, bf_lo(ulo), acc.x);
        acc.y = fmaf(v, bf_hi(ulo), acc.y);
        acc.z = fmaf(v, bf_lo(uhi), acc.z);
        acc.w = fmaf(v, bf_hi(uhi), acc.w);
    }
}

__global__ __launch_bounds__(256) void agg_kernel(const unsigned short* __restrict__ hidb,
                                                  const int* __restrict__ deg,
                                                  const int2* __restrict__ bucket,
                                                  const float* __restrict__ b,
                                                  float* __restrict__ out) {
    const int tid = threadIdx.x;
    const int lane = tid & 63;
    const int wid = tid >> 6;
    const int q = lane >> 4;        // quarter = which of the wave's 4 rows
    const int l = lane & 15;        // dims 4l .. 4l+3
    const int row = blockIdx.x * 16 + wid * 4 + q;   // grid covers exactly 50000

    const int d = min(deg[row], CAP);
    const int2* __restrict__ ep = bucket + (size_t)row * CAP;

    // wave-uniform max degree over the 4 quarters (uniform trip counts)
    int dmax = d;
    dmax = max(dmax, __shfl_xor(dmax, 16));
    dmax = max(dmax, __shfl_xor(dmax, 32));

    // stage first 32 edge slots to registers; beyond-deg entries gated off
    const int2 pa = ep[l];
    const int2 pb = ep[16 + l];

    float4 acc = make_float4(0.f, 0.f, 0.f, 0.f);

    proc16(hidb, pa, 0, q, l, d, acc);                  // unconditional window
    if (dmax > 16) proc16(hidb, pb, 16, q, l, d, acc);  // one guarded window
    for (int base = 32; base < dmax; base += 16) {      // rare tail (P ~ 1e-4)
        const int2 pc = ep[base + l];
        proc16(hidb, pc, base, q, l, d, acc);
    }

    const float4 bb = *(const float4*)&b[4 * l];
    float4 o;
    o.x = fmaxf(acc.x + bb.x, 0.f);
    o.y = fmaxf(acc.y + bb.y, 0.f);
    o.z = fmaxf(acc.z + bb.z, 0.f);
    o.w = fmaxf(acc.w + bb.w, 0.f);
    *(float4*)&out[(size_t)row * OUT_DIM + 4 * l] = o;
}

extern "C" void kernel_launch(void* const* d_in, const int* in_sizes, int n_in,
                              void* d_out, int out_size, void* d_ws, size_t ws_size,
                              hipStream_t stream) {
    const float* x    = (const float*)d_in[0];
    const int*   erow = (const int*)d_in[1];
    const int*   ecol = (const int*)d_in[2];
    const float* eval = (const float*)d_in[3];
    const float* w    = (const float*)d_in[4];
    const float* b    = (const float*)d_in[5];
    float* out = (float*)d_out;

    char* ws = (char*)d_ws;
    unsigned short* hidb = (unsigned short*)(ws + OFF_HID);
    int*  deg    = (int*)(ws + OFF_DEG);
    int2* bucket = (int2*)(ws + OFF_BKT);

    hipMemsetAsync(deg, 0, N_NODES * sizeof(int), stream);

    // 1) fused: GEMM (blocks 0..783) overlapped with XCD-partitioned bucket
    fused_kernel<<<TOTAL_BLOCKS, 256, 0, stream>>>(
        x, w, hidb, erow, ecol, eval, deg, bucket);

    // 2) per-row gather-accumulate (4 rows/wave, 16-deep gather windows)
    agg_kernel<<<N_NODES / 16, 256, 0, stream>>>(hidb, deg, bucket, b, out);
}

// Round 8
// 143.143 us; speedup vs baseline: 1.0048x; 1.0048x over previous
//
#include <hip/hip_runtime.h>

#define N_NODES 50000
#define N_EDGES 800000
#define IN_DIM 128
#define OUT_DIM 64
#define CAP 64            // max row degree ~35 (Binomial(800k,1/50k), mean 16), 64 is safe
#define PARTS 8           // row partitions == XCD count
#define ROWS_PER_PART 6250
#define CHUNKS 512
#define EDGES_PER_CHUNK 1563   // 512*1563 = 800256 >= 800000 (guarded)

// Block layout: GEMM blocks FIRST so they are co-resident with the bucket
// blocks. 784%8==0 keeps the bucket blocks' blockIdx%8 == XCD mapping intact.
#define GEMM_BLOCKS 784                  // 784*4 waves = 3136 >= 3125 groups
#define BUCKET_BLOCKS (CHUNKS * PARTS)   // 4096
#define TOTAL_BLOCKS (GEMM_BLOCKS + BUCKET_BLOCKS)

// workspace layout (bytes), 16B-aligned
#define OFF_HID 0u          // bf16 hidden: 50000*64*2 = 6,400,000
#define OFF_DEG 6400000u    // int deg: 200,000
#define OFF_BKT 6600192u    // int2 bucket: 12500 groups * 4*CAP * 8B = 25,600,000

typedef short short8 __attribute__((ext_vector_type(8)));
typedef float f32x4 __attribute__((ext_vector_type(4)));

__device__ __forceinline__ unsigned short bf_rne(float f) {
    unsigned u = __float_as_uint(f);
    u += 0x7fffu + ((u >> 16) & 1u);   // round-to-nearest-even
    return (unsigned short)(u >> 16);
}
__device__ __forceinline__ float bf_lo(unsigned u) { return __uint_as_float(u << 16); }
__device__ __forceinline__ float bf_hi(unsigned u) { return __uint_as_float(u & 0xffff0000u); }

// Bucket layout, GROUP-INTERLEAVED by 4 rows:
//   slot `pos` of row `r` lives at bucket[(r>>2)*(4*CAP) + pos*4 + (r&3)].
// A 64-B line = 2 slot-planes x 4 rows; all 4 rows of a group populate their
// low slots, so lines for pos < min-deg-of-group receive ALL 8 entries ->
// they can merge into full lines in the home XCD's L2 (the old [row][slot]
// layout made full lines impossible: a row's 1-3 lines never filled, hence
// the measured 45 MB HBM writes for a 6.4 MB payload).
// Read side: one wave's staged slots 0..31 x 4 rows = two contiguous 512-B
// regions -> perfectly coalesced agg stage reads.
__device__ __forceinline__ size_t bslot(int r, int pos) {
    return (size_t)(r >> 2) * (4 * CAP) + pos * 4 + (r & 3);
}

// ---------------------------------------------------------------------------
// FUSED kernel. blocks [0, 784): MFMA GEMM hidden = x @ w.
// blocks [784, 784+4096): edge bucketing, XCD-partitioned (part = bb&7 ==
// XCD). Each partition re-reads the full edge list (redundancy L3-absorbed)
// but writes ONLY its own 3.2 MB bucket section (R5: removing this = +20 us).
// 6 edges/thread loaded up-front, 6 independent atomic->store chains.
// ---------------------------------------------------------------------------
__global__ __launch_bounds__(256) void fused_kernel(
        const float* __restrict__ x, const float* __restrict__ w,
        unsigned short* __restrict__ hidb,
        const int* __restrict__ erow, const int* __restrict__ ecol,
        const float* __restrict__ eval,
        int* __restrict__ deg, int2* __restrict__ bucket) {
    if (blockIdx.x >= GEMM_BLOCKS) {
        const int bb = blockIdx.x - GEMM_BLOCKS;
        const int part = bb & (PARTS - 1);           // == XCD id
        const int chunk = bb >> 3;
        const int rlo = part * ROWS_PER_PART;
        const int e0 = chunk * EDGES_PER_CHUNK;

        int r[6], c[6];
        float v[6];
        bool ok[6];
        #pragma unroll
        for (int t = 0; t < 6; ++t) {
            const int e = e0 + threadIdx.x + t * 256;   // max 1535 < 1563
            ok[t] = e < N_EDGES;
            r[t] = ok[t] ? erow[e] : -1;
            c[t] = ok[t] ? ecol[e] : 0;
            v[t] = ok[t] ? eval[e] : 0.f;
        }
        #pragma unroll
        for (int t = 0; t < 6; ++t) {
            if (ok[t] && (unsigned)(r[t] - rlo) < (unsigned)ROWS_PER_PART) {
                const int pos = atomicAdd(&deg[r[t]], 1);
                if (pos < CAP)
                    bucket[bslot(r[t], pos)] = make_int2(c[t], __float_as_int(v[t]));
            }
        }
        // tail: slots 1536..1562 (tid < 27)
        const int it = threadIdx.x + 1536;
        const int e = e0 + it;
        if (it < EDGES_PER_CHUNK && e < N_EDGES) {
            const int rt = erow[e];
            const int ct = ecol[e];
            const float vt = eval[e];
            if ((unsigned)(rt - rlo) < (unsigned)ROWS_PER_PART) {
                const int pos = atomicAdd(&deg[rt], 1);
                if (pos < CAP) bucket[bslot(rt, pos)] = make_int2(ct, __float_as_int(vt));
            }
        }
        return;
    }

    // ---- GEMM path: hidden(bf16) = x @ w, one wave per 16-node group ----
    __shared__ __attribute__((aligned(16))) unsigned short smem[16 * 64 * 8];  // 16 KB

    const int tid = threadIdx.x;
    const int lane = tid & 63;
    const int wid = tid >> 6;

    // stage w into B-fragment order — coalesced float4 global reads,
    // scattered cheap LDS u16 writes.
    #pragma unroll
    for (int it = 0; it < 8; ++it) {
        const int e = it * 1024 + tid * 4;
        const f32x4 wv = *(const f32x4*)(w + e);
        const int k = e >> 6;
        const int n0 = e & 63;
        const int c = k >> 5, j = k & 7, lhi = ((k >> 3) & 3) * 16;
        #pragma unroll
        for (int m = 0; m < 4; ++m) {
            const int n = n0 + m;
            const int t = n >> 4;
            const int ln = lhi + (n & 15);
            smem[((c * 4 + t) * 64 + ln) * 8 + j] = bf_rne(wv[m]);
        }
    }
    __syncthreads();

    const int group = blockIdx.x * 4 + wid;   // 16-node group id

    short8 bf[16];
    if (group < N_NODES / 16) {
        #pragma unroll
        for (int f = 0; f < 16; ++f)
            bf[f] = *(const short8*)&smem[(f * 64 + lane) * 8];
    }
    __syncthreads();   // all waves have frags in regs -> smem reusable

    if (group < N_NODES / 16) {
        const int node0 = group * 16;
        f32x4 acc[4] = {{0, 0, 0, 0}, {0, 0, 0, 0}, {0, 0, 0, 0}, {0, 0, 0, 0}};

        #pragma unroll
        for (int c = 0; c < 4; ++c) {
            const float* xr = x + (size_t)(node0 + (lane & 15)) * IN_DIM + c * 32 + (lane >> 4) * 8;
            const f32x4 a0 = __builtin_nontemporal_load((const f32x4*)xr);   // read-once
            const f32x4 a1 = __builtin_nontemporal_load((const f32x4*)(xr + 4));
            short8 af;
            af[0] = (short)bf_rne(a0[0]); af[1] = (short)bf_rne(a0[1]);
            af[2] = (short)bf_rne(a0[2]); af[3] = (short)bf_rne(a0[3]);
            af[4] = (short)bf_rne(a1[0]); af[5] = (short)bf_rne(a1[1]);
            af[6] = (short)bf_rne(a1[2]); af[7] = (short)bf_rne(a1[3]);
            #pragma unroll
            for (int t = 0; t < 4; ++t)
                acc[t] = __builtin_amdgcn_mfma_f32_16x16x32_bf16(af, bf[c * 4 + t], acc[t], 0, 0, 0);
        }

        // epilogue: D[m][n] -> smem bounce (wave-private slice) -> global
        unsigned short* obuf = smem + wid * 1024;
        #pragma unroll
        for (int t = 0; t < 4; ++t)
            #pragma unroll
            for (int r = 0; r < 4; ++r)
                obuf[((lane >> 4) * 4 + r) * 64 + t * 16 + (lane & 15)] = bf_rne(acc[t][r]);
        const uint4 o0 = *(const uint4*)&obuf[lane * 16];
        const uint4 o1 = *(const uint4*)&obuf[lane * 16 + 8];
        char* dst = (char*)hidb + (size_t)node0 * (OUT_DIM * 2) + lane * 32;
        *(uint4*)dst = o0;
        *(uint4*)(dst + 16) = o1;
    }
}

// ---------------------------------------------------------------------------
// Aggregate: 4 rows per wave == ONE bucket group (quarter q = row, 16 lanes
// x 8 B cover the 128-B hidden row). Bucket stage reads are now CONTIGUOUS:
// gp[lane] covers slots 0-15 x 4 rows (512 B), gp[64+lane] slots 16-31.
// Lane holding (row q, slot e) is e*4+q. Gathers in 16-deep windows.
// ---------------------------------------------------------------------------
__device__ __forceinline__ void proc16(const unsigned short* __restrict__ hidb,
                                       int2 P, int base,
                                       int q, int l, int d, float4& acc) {
    unsigned long long u[16];
    float vv[16];
    #pragma unroll
    for (int e = 0; e < 16; ++e) {
        const int src = (e << 2) | q;        // lane holding (row q, slot base+e)
        int c = __shfl(P.x, src);
        const int vi = __shfl(P.y, src);
        const bool act = (base + e) < d;
        c = act ? c : 0;
        vv[e] = act ? __int_as_float(vi) : 0.f;
        u[e] = *(const unsigned long long*)&hidb[(size_t)c * OUT_DIM + 4 * l];
    }
    #pragma unroll
    for (int e = 0; e < 16; ++e) {
        const float v = vv[e];
        const unsigned ulo = (unsigned)u[e];
        const unsigned uhi = (unsigned)(u[e] >> 32);
        acc.x = fmaf(v, bf_lo(ulo), acc.x);
        acc.y = fmaf(v, bf_hi(ulo), acc.y);
        acc.z = fmaf(v, bf_lo(uhi), acc.z);
        acc.w = fmaf(v, bf_hi(uhi), acc.w);
    }
}

__global__ __launch_bounds__(256) void agg_kernel(const unsigned short* __restrict__ hidb,
                                                  const int* __restrict__ deg,
                                                  const int2* __restrict__ bucket,
                                                  const float* __restrict__ b,
                                                  float* __restrict__ out) {
    const int tid = threadIdx.x;
    const int lane = tid & 63;
    const int wid = tid >> 6;
    const int q = lane >> 4;        // row within the wave's group
    const int l = lane & 15;        // dims 4l .. 4l+3
    const int grp = blockIdx.x * 4 + wid;            // bucket group (4 rows)
    const int row = grp * 4 + q;                     // grid covers exactly 50000

    const int d = min(deg[row], CAP);
    const int2* __restrict__ gp = bucket + (size_t)grp * (4 * CAP);

    // wave-uniform max degree over the 4 rows (uniform trip counts)
    int dmax = d;
    dmax = max(dmax, __shfl_xor(dmax, 16));
    dmax = max(dmax, __shfl_xor(dmax, 32));

    // stage first 32 slots x 4 rows: two contiguous 512-B reads
    const int2 pa = gp[lane];        // (row lane&3, slot lane>>2)
    const int2 pb = gp[64 + lane];   // (row lane&3, slot 16+(lane>>2))

    float4 acc = make_float4(0.f, 0.f, 0.f, 0.f);

    proc16(hidb, pa, 0, q, l, d, acc);                  // unconditional window
    if (dmax > 16) proc16(hidb, pb, 16, q, l, d, acc);  // one guarded window
    for (int base = 32; base < dmax; base += 16) {      // rare tail (P ~ 1e-4)
        const int2 pc = gp[base * 4 + lane];
        proc16(hidb, pc, base, q, l, d, acc);
    }

    const float4 bb = *(const float4*)&b[4 * l];
    float4 o;
    o.x = fmaxf(acc.x + bb.x, 0.f);
    o.y = fmaxf(acc.y + bb.y, 0.f);
    o.z = fmaxf(acc.z + bb.z, 0.f);
    o.w = fmaxf(acc.w + bb.w, 0.f);
    *(float4*)&out[(size_t)row * OUT_DIM + 4 * l] = o;
}

extern "C" void kernel_launch(void* const* d_in, const int* in_sizes, int n_in,
                              void* d_out, int out_size, void* d_ws, size_t ws_size,
                              hipStream_t stream) {
    const float* x    = (const float*)d_in[0];
    const int*   erow = (const int*)d_in[1];
    const int*   ecol = (const int*)d_in[2];
    const float* eval = (const float*)d_in[3];
    const float* w    = (const float*)d_in[4];
    const float* b    = (const float*)d_in[5];
    float* out = (float*)d_out;

    char* ws = (char*)d_ws;
    unsigned short* hidb = (unsigned short*)(ws + OFF_HID);
    int*  deg    = (int*)(ws + OFF_DEG);
    int2* bucket = (int2*)(ws + OFF_BKT);

    hipMemsetAsync(deg, 0, N_NODES * sizeof(int), stream);

    // 1) fused: GEMM (blocks 0..783) overlapped with XCD-partitioned bucket
    fused_kernel<<<TOTAL_BLOCKS, 256, 0, stream>>>(
        x, w, hidb, erow, ecol, eval, deg, bucket);

    // 2) per-row gather-accumulate (4 rows/wave == 1 group, coalesced stage)
    agg_kernel<<<N_NODES / 16, 256, 0, stream>>>(hidb, deg, bucket, b, out);
}